// Round 5
// baseline (118.434 us; speedup 1.0000x reference)
//
#include <hip/hip_runtime.h>

#define Bb 4
#define AT 384
#define NBR 24
#define FEAT 128
#define ROWQ (FEAT / 4)              // 32 float4 per feature row
#define PANELQ (NBR * ROWQ)          // 768 float4 per (b,a) edge panel
#define OUTQ ((size_t)Bb * AT * NBR * NBR * ROWQ)   // 28,311,552 float4

typedef float vfloat4 __attribute__((ext_vector_type(4)));

// ---------------- Kernel 1: pure zero-fill ----------------
// Structurally identical to rocclr fillBuffer: grid-stride, 16B stores,
// zero data dependencies. Proven ~6.8 TB/s on this harness.
__global__ __launch_bounds__(256) void fill_kernel(
    vfloat4* __restrict__ out, unsigned int n)
{
    const vfloat4 zero = (vfloat4)(0.f);
    unsigned int idx = blockIdx.x * 256u + threadIdx.x;
    const unsigned int stride = gridDim.x * 256u;
    for (; idx < n; idx += stride)
        out[idx] = zero;
}

// ---------------- Kernel 2: mask + sparse scatter ----------------
// One block per (b,a). Builds the 24x24 match mask, appends matched (j,i)
// pairs to an LDS list, then copies edge[b,a,i,:] -> out[b,a,j,i,:] for
// each pair with one 32-lane group per row (32 x float4 = 512 B).
__global__ __launch_bounds__(256) void scatter_kernel(
    const vfloat4* __restrict__ edge,   // (B, AT, NBR, FEAT) as float4
    const int*     __restrict__ nbr,    // (B, AT, NBR)
    const float*   __restrict__ cell,   // (B, AT, NBR, 3)
    vfloat4*       __restrict__ out)    // (B, AT, NBR_j, NBR_i, FEAT)
{
    const int ba = blockIdx.x;          // b*AT + a
    const int b  = ba / AT;
    const int t  = threadIdx.x;

    __shared__ int   s_nbr[NBR];
    __shared__ float s_cell[NBR][3];
    __shared__ int   s_nbrj[NBR][NBR];
    __shared__ float s_cellj[NBR][NBR][3];
    __shared__ int   s_list[NBR * NBR]; // packed (j<<5)|i
    __shared__ int   s_cnt;

    if (t == 0) s_cnt = 0;
    if (t < NBR) {
        s_nbr[t]     = nbr[ba * NBR + t];
        s_cell[t][0] = cell[(ba * NBR + t) * 3 + 0];
        s_cell[t][1] = cell[(ba * NBR + t) * 3 + 1];
        s_cell[t][2] = cell[(ba * NBR + t) * 3 + 2];
    }
    __syncthreads();

    // stage neighbors-of-neighbors
    for (int q = t; q < NBR * NBR; q += 256) {
        const int j = q / NBR;
        const int k = q % NBR;
        const int base = (b * AT + s_nbr[j]) * NBR + k;
        s_nbrj[j][k]     = nbr[base];
        s_cellj[j][k][0] = cell[base * 3 + 0];
        s_cellj[j][k][1] = cell[base * 3 + 1];
        s_cellj[j][k][2] = cell[base * 3 + 2];
    }
    __syncthreads();

    // mask[j][i]: append matched pairs to the LDS list
    for (int p = t; p < NBR * NBR; p += 256) {
        const int j = p / NBR;
        const int i = p % NBR;
        if (i != j) {
            const int   myidx = s_nbr[i];
            const float c0 = s_cell[i][0];
            const float c1 = s_cell[i][1];
            const float c2 = s_cell[i][2];
            int m = 0;
            #pragma unroll
            for (int k = 0; k < NBR; ++k) {
                if (s_nbrj[j][k] == myidx &&
                    s_cellj[j][k][0] == c0 &&
                    s_cellj[j][k][1] == c1 &&
                    s_cellj[j][k][2] == c2) { m = 1; }
            }
            if (m) {
                const int slot = atomicAdd(&s_cnt, 1);
                s_list[slot] = (j << 5) | i;
            }
        }
    }
    __syncthreads();

    // copy matched rows: one 32-lane group per row, 8 groups per block
    const int cnt  = s_cnt;
    const int g    = t >> 5;
    const int lane = t & 31;
    const vfloat4* __restrict__ erow = edge + (size_t)ba * PANELQ;
    for (int p = g; p < cnt; p += 8) {
        const int ji = s_list[p];
        const int j  = ji >> 5;
        const int i  = ji & 31;
        const vfloat4 v = erow[i * ROWQ + lane];
        out[((size_t)(ba * NBR + j) * NBR + i) * ROWQ + lane] = v;
    }
}

extern "C" void kernel_launch(void* const* d_in, const int* in_sizes, int n_in,
                              void* d_out, int out_size, void* d_ws, size_t ws_size,
                              hipStream_t stream) {
    const vfloat4* edge = (const vfloat4*)d_in[0];
    const int*     nbr  = (const int*)d_in[1];
    const float*   cell = (const float*)d_in[2];
    vfloat4*       out  = (vfloat4*)d_out;

    // 1) zero-fill the whole output (453 MB) with a dependency-free stream
    fill_kernel<<<2048, 256, 0, stream>>>(out, (unsigned int)OUTQ);
    // 2) scatter the ~0.2%-dense matched rows on top
    scatter_kernel<<<Bb * AT, 256, 0, stream>>>(edge, nbr, cell, out);
}

// Round 6
// 94.111 us; speedup vs baseline: 1.2584x; 1.2584x over previous
//
#include <hip/hip_runtime.h>

#define Bb 4
#define AT 384
#define NBR 24
#define FEAT 128
#define ROWQ (FEAT / 4)          // 32 float4 per feature row
#define JROWQ (NBR * ROWQ)       // 768 float4 per (b,a,j) output block (and per (b,a) edge panel)

typedef float vfloat4 __attribute__((ext_vector_type(4)));

// One 64-thread block (1 wave) per (b,a,j).
// Prologue: stage the 24 neighbor rows of atom nbr[b,a,j], each of lanes 0..23
// checks its own i against all 24 k's; __ballot builds the 24-bit mask in an
// SGPR. Store phase: 12 independent dwordx4 stores per lane (12 KB/block),
// with a branchless pure-fill fast path for the ~95% of blocks whose mask is 0.
__global__ __launch_bounds__(64) void edgejk_kernel(
    const vfloat4* __restrict__ edge,   // (B, AT, NBR, FEAT) as float4
    const int*     __restrict__ nbr,    // (B, AT, NBR)
    const float*   __restrict__ cell,   // (B, AT, NBR, 3)
    vfloat4*       __restrict__ out)    // (B, AT, NBR_j, NBR_i, FEAT)
{
    const int blk = blockIdx.x;         // (b*AT + a)*NBR + j
    const int j   = blk % NBR;
    const int ba  = blk / NBR;
    const int b   = ba / AT;
    const int t   = threadIdx.x;        // 0..63

    __shared__ int   s_nbrj[NBR];
    __shared__ float s_cellj[NBR][3];

    // per-lane own-neighbor data (lane t == i), independent of jatom -> overlaps
    int   myidx = -2;
    float c0 = 0.f, c1 = 0.f, c2 = 0.f;
    if (t < NBR) {
        myidx = nbr[ba * NBR + t];
        c0 = cell[(ba * NBR + t) * 3 + 0];
        c1 = cell[(ba * NBR + t) * 3 + 1];
        c2 = cell[(ba * NBR + t) * 3 + 2];
    }

    const int jatom = nbr[ba * NBR + j];   // wave-uniform

    if (t < NBR) {
        const int base = (b * AT + jatom) * NBR + t;
        s_nbrj[t]     = nbr[base];
        s_cellj[t][0] = cell[base * 3 + 0];
        s_cellj[t][1] = cell[base * 3 + 1];
        s_cellj[t][2] = cell[base * 3 + 2];
    }
    __syncthreads();

    int match = 0;
    if (t < NBR && t != j) {
        #pragma unroll
        for (int k = 0; k < NBR; ++k) {
            if (s_nbrj[k] == myidx &&
                s_cellj[k][0] == c0 &&
                s_cellj[k][1] == c1 &&
                s_cellj[k][2] == c2) { match = 1; }
        }
    }
    const unsigned long long w = __ballot(match != 0);   // bit i = mask[j][i]

    const vfloat4* __restrict__ erow = edge + (size_t)ba * JROWQ;
    vfloat4*       __restrict__ orow = out  + (size_t)blk * JROWQ;
    const vfloat4 zero = (vfloat4)(0.f);

    if (w == 0ull) {
        // pure fill: 12 independent dwordx4 stores, no data dependencies
        #pragma unroll
        for (int it = 0; it < 12; ++it)
            orow[it * 64 + t] = zero;
    } else {
        #pragma unroll
        for (int it = 0; it < 12; ++it) {
            const int q = it * 64 + t;     // [0, 768)
            const int i = q >> 5;          // neighbor row (32 float4 each)
            vfloat4 v = zero;
            if ((w >> i) & 1ull) v = erow[q];
            orow[q] = v;
        }
    }
}

extern "C" void kernel_launch(void* const* d_in, const int* in_sizes, int n_in,
                              void* d_out, int out_size, void* d_ws, size_t ws_size,
                              hipStream_t stream) {
    const vfloat4* edge = (const vfloat4*)d_in[0];
    const int*     nbr  = (const int*)d_in[1];
    const float*   cell = (const float*)d_in[2];
    vfloat4*       out  = (vfloat4*)d_out;

    const int nblocks = Bb * AT * NBR;   // 36864 blocks, 1 wave each
    edgejk_kernel<<<nblocks, 64, 0, stream>>>(edge, nbr, cell, out);
}